// Round 10
// baseline (395.756 us; speedup 1.0000x reference)
//
#include <hip/hip_runtime.h>
#include <hip/hip_bf16.h>
#include <math.h>

#define DIM    256
#define DEPTH  5
#define FANOUT 10
#define VOCAB  257
#define BB     16
#define TT     2048
#define NEXP   8
#define HID    512
#define TOPK   2
#define CAP    5   // ceil(16*2/8*1.1)
#define TSTR   260 // padded table row stride (16B-aligned, float4-clean)

__device__ __forceinline__ float sigm(float x) { return 1.f / (1.f + expf(-x)); }

// partial dot over k in [k0,k0+64): four explicit 16-wide load-then-FMA batches.
// ~35 live VGPRs -> fits the 64-VGPR budget of a 1024-thread block (no spill;
// R5's 32-wide variant at 64+ live regs spilled -- lesson applied).
__device__ __forceinline__ float dotcol64(const float* sv, const float* __restrict__ W,
                                          int col, int k0, int stride) {
  float acc = 0.f;
#pragma unroll
  for (int h = 0; h < 4; ++h) {
    int kb = k0 + h * 16;
    float wv[16], s[16];
#pragma unroll
    for (int i = 0; i < 16; ++i) wv[i] = W[(size_t)(kb + i) * stride + col];
#pragma unroll
    for (int i = 0; i < 16; ++i) s[i] = sv[kb + i];
#pragma unroll
    for (int i = 0; i < 16; ++i) acc = fmaf(s[i], wv[i], acc);
  }
  return acc;
}

// ------ collapsed fractal (context fused in): 16 blocks x 1024 threads -------
// R6-proven structure (scalar loads, fused in_proj), 16-wide MLP batches.
__global__ void __launch_bounds__(1024) k_fractal(
    const int* __restrict__ tokens, const float* __restrict__ embed,
    const float* __restrict__ pin_w, const float* __restrict__ pin_b,
    const float* __restrict__ pch_w, const float* __restrict__ pch_b,
    const float* __restrict__ depth_bias,
    const float* __restrict__ v_w, const float* __restrict__ v_b,
    const float* __restrict__ o_w, const float* __restrict__ o_b,
    const float* __restrict__ level_gate, const float* __restrict__ depth_gate,
    const float* __restrict__ in_proj_w, const float* __restrict__ in_proj_b,
    const float* __restrict__ out_proj_w, const float* __restrict__ out_proj_b,
    const float* __restrict__ ln_g, const float* __restrict__ ln_b,
    const float* __restrict__ ic_gate,
    float* __restrict__ rootA) {
  int b = blockIdx.x;
  int tid = threadIdx.x;
  int d = tid & 255;
  int ks = tid >> 8;       // 0..3
  int k0 = ks * 64;
  __shared__ int cnt[VOCAB];
  __shared__ float sv[DIM];
  __shared__ float basev[DIM];
  __shared__ float ym[DEPTH][DIM];
  __shared__ float q0v[DIM], kh[DEPTH][DIM], vh[DEPTH][DIM];
  __shared__ float red4[4][DIM];
  __shared__ float red11[4][11][DIM];   // fused in_proj reduction
  __shared__ float zsv[DIM];
  __shared__ float aw[16];
  __shared__ float redl[8];

  // ---- token histogram ----
  for (int i = tid; i < VOCAB; i += 1024) cnt[i] = 0;
  __syncthreads();
  for (int t = tid; t < TT; t += 1024) atomicAdd(&cnt[tokens[b * TT + t]], 1);
  __syncthreads();
  // ---- context = (hist @ embed)/T, branch-free, 16-wide batches ----
  {
    float acc = 0.f;
#pragma unroll
    for (int h = 0; h < 4; ++h) {
      int vb = k0 + h * 16;
      float ev[16], cv[16];
#pragma unroll
      for (int i = 0; i < 16; ++i) ev[i] = embed[(size_t)(vb + i) * DIM + d];
#pragma unroll
      for (int i = 0; i < 16; ++i) cv[i] = (float)cnt[vb + i];
#pragma unroll
      for (int i = 0; i < 16; ++i) acc = fmaf(cv[i], ev[i], acc);
    }
    if (ks == 0) acc = fmaf((float)cnt[256], embed[(size_t)256 * DIM + d], acc);
    red4[ks][d] = acc;
  }
  __syncthreads();
  if (ks == 0)
    sv[d] = (red4[0][d] + red4[1][d] + red4[2][d] + red4[3][d]) * (1.0f / (float)TT);
  __syncthreads();

  // base = context @ pin_w + pin_b ; level-4 elementwise (child_agg == 0)
  red4[ks][d] = dotcol64(sv, pin_w, d, k0, DIM);
  __syncthreads();
  if (ks == 0) {
    float base = red4[0][d] + red4[1][d] + red4[2][d] + red4[3][d] + pin_b[d];
    basev[d] = base;
    float u = (base + depth_bias[4 * DIM + d] + pch_b[d]) * sigm(level_gate[4]);
    sv[d] = fmaxf(u, 0.f);
  }
  __syncthreads();
  red4[ks][d] = dotcol64(sv, o_w, d, k0, DIM);
  __syncthreads();
  if (ks == 0) {
    float y = red4[0][d] + red4[1][d] + red4[2][d] + red4[3][d] + o_b[d];
    ym[4][d] = y;
    sv[d] = y;
  }
  __syncthreads();
  for (int l = 3; l >= 0; --l) {
    red4[ks][d] = dotcol64(sv, v_w, d, k0, DIM);
    __syncthreads();
    if (ks == 0) {
      float vv = red4[0][d] + red4[1][d] + red4[2][d] + red4[3][d] + v_b[d];
      sv[d] = sigm(depth_gate[l * DIM + d]) * vv;   // uniform softmax -> child = v
    }
    __syncthreads();
    red4[ks][d] = dotcol64(sv, pch_w, d, k0, DIM);
    __syncthreads();
    if (ks == 0) {
      float t = red4[0][d] + red4[1][d] + red4[2][d] + red4[3][d] + pch_b[d];
      float u = (basev[d] + depth_bias[l * DIM + d] + t) * sigm(level_gate[l]);
      sv[d] = fmaxf(u, 0.f);
    }
    __syncthreads();
    red4[ks][d] = dotcol64(sv, o_w, d, k0, DIM);
    __syncthreads();
    if (ks == 0) {
      float y = red4[0][d] + red4[1][d] + red4[2][d] + red4[3][d] + o_b[d];
      ym[l][d] = y;
      sv[d] = y;
    }
    __syncthreads();
  }
  // ---- in_proj, ALL levels in ONE pass over the weights (R6-proven) ----
  {
    float aq = 0.f;
    float ak0 = 0.f, ak1 = 0.f, ak2 = 0.f, ak3 = 0.f, ak4 = 0.f;
    float av0 = 0.f, av1 = 0.f, av2 = 0.f, av3 = 0.f, av4 = 0.f;
#pragma unroll
    for (int h = 0; h < 8; ++h) {
      int kb = k0 + h * 8;
      float wq[8], wk[8], wv8[8];
#pragma unroll
      for (int i = 0; i < 8; ++i) {
        const float* wrow = in_proj_w + (size_t)(kb + i) * 768;
        wq[i] = wrow[d]; wk[i] = wrow[256 + d]; wv8[i] = wrow[512 + d];
      }
#pragma unroll
      for (int i = 0; i < 8; ++i) {
        float z0 = ym[0][kb + i];
        aq  = fmaf(z0, wq[i], aq);
        ak0 = fmaf(z0, wk[i], ak0);
        av0 = fmaf(z0, wv8[i], av0);
        float z1 = ym[1][kb + i];
        ak1 = fmaf(z1, wk[i], ak1);
        av1 = fmaf(z1, wv8[i], av1);
        float z2 = ym[2][kb + i];
        ak2 = fmaf(z2, wk[i], ak2);
        av2 = fmaf(z2, wv8[i], av2);
        float z3 = ym[3][kb + i];
        ak3 = fmaf(z3, wk[i], ak3);
        av3 = fmaf(z3, wv8[i], av3);
        float z4 = ym[4][kb + i];
        ak4 = fmaf(z4, wk[i], ak4);
        av4 = fmaf(z4, wv8[i], av4);
      }
    }
    red11[ks][0][d] = ak0; red11[ks][1][d] = ak1; red11[ks][2][d] = ak2;
    red11[ks][3][d] = ak3; red11[ks][4][d] = ak4;
    red11[ks][5][d] = av0; red11[ks][6][d] = av1; red11[ks][7][d] = av2;
    red11[ks][8][d] = av3; red11[ks][9][d] = av4;
    red11[ks][10][d] = aq;
  }
  __syncthreads();
  for (int idx = tid; idx < 11 * DIM; idx += 1024) {
    int c = idx >> 8, dd = idx & 255;
    float sum = red11[0][c][dd] + red11[1][c][dd] + red11[2][c][dd] + red11[3][c][dd];
    if (c < 5)       kh[c][dd]     = sum + in_proj_b[256 + dd];
    else if (c < 10) vh[c - 5][dd] = sum + in_proj_b[512 + dd];
    else             q0v[dd]       = sum + in_proj_b[dd];
  }
  __syncthreads();
  if (tid < 10) {  // scores for (head, level)
    int h = tid / 5, l = tid - h * 5;
    float s = 0.f;
    for (int j = 0; j < 128; ++j) s = fmaf(q0v[h * 128 + j], kh[l][h * 128 + j], s);
    aw[tid] = s * 0.08838834764831845f;  // 1/sqrt(128)
  }
  __syncthreads();
  if (tid < 2) {  // softmax per head
    float m = aw[tid * 5];
    for (int l = 1; l < 5; ++l) m = fmaxf(m, aw[tid * 5 + l]);
    float e[5], ssum = 0.f;
    for (int l = 0; l < 5; ++l) { e[l] = expf(aw[tid * 5 + l] - m); ssum += e[l]; }
    for (int l = 0; l < 5; ++l) aw[tid * 5 + l] = e[l] / ssum;
  }
  __syncthreads();
  if (ks == 0) {
    int h = d >> 7;
    float z2 = 0.f;
    for (int l = 0; l < 5; ++l) z2 = fmaf(aw[h * 5 + l], vh[l][d], z2);
    sv[d] = z2;
  }
  __syncthreads();
  red4[ks][d] = dotcol64(sv, out_proj_w, d, k0, DIM);
  __syncthreads();
  if (ks == 0) {
    float z2p = red4[0][d] + red4[1][d] + red4[2][d] + red4[3][d] + out_proj_b[d];
    zsv[d] = ym[0][d] + z2p;
  }
  __syncthreads();
  // layernorm over 256 (waves 0..3 only)
  float zs = 0.f, df = 0.f, mu = 0.f;
  if (tid < 256) {
    zs = zsv[tid];
    float v = zs;
    for (int o = 32; o > 0; o >>= 1) v += __shfl_down(v, o, 64);
    if ((tid & 63) == 0) redl[tid >> 6] = v;
  }
  __syncthreads();
  if (tid < 256) {
    mu = (redl[0] + redl[1] + redl[2] + redl[3]) * (1.f / 256.f);
    df = zs - mu;
  }
  __syncthreads();
  if (tid < 256) {
    float v = df * df;
    for (int o = 32; o > 0; o >>= 1) v += __shfl_down(v, o, 64);
    if ((tid & 63) == 0) redl[tid >> 6] = v;
  }
  __syncthreads();
  if (tid < 256) {
    float var = (redl[0] + redl[1] + redl[2] + redl[3]) * (1.f / 256.f);
    float zn = df / sqrtf(var + 1e-5f) * ln_g[tid] + ln_b[tid];
    rootA[b * DIM + tid] = ym[0][tid] + sigm(ic_gate[0]) * zn;
  }
}

// ------- MoE gating + root2 init: exact lax.top_k semantics -------------------
__global__ void __launch_bounds__(1024) k_gate(const float* __restrict__ rootA,
                                               const float* __restrict__ gate_w,
                                               const float* __restrict__ gate_b,
                                               int* __restrict__ etok,
                                               float* __restrict__ ewt,
                                               float* __restrict__ root2) {
  __shared__ float red[BB * NEXP][9];   // pad to 9 -> conflict-light
  __shared__ float sc[BB * NEXP];
  __shared__ float gs[BB * TOPK];
  __shared__ int gidx[BB * TOPK];
  int tid = threadIdx.x;
  int be = tid >> 3, ks = tid & 7;      // be = b*8+e, 8-way K-split
  int b = be >> 3, e = be & 7;
  {
    float acc = 0.f;
#pragma unroll 8
    for (int i = 0; i < 32; ++i) {
      int k = ks * 32 + i;
      acc = fmaf(rootA[b * DIM + k], gate_w[k * NEXP + e], acc);
    }
    red[be][ks] = acc;
  }
  // root2 = rootA (experts atomically add on top)
  for (int i = tid; i < BB * DIM; i += 1024) root2[i] = rootA[i];
  __syncthreads();
  if (tid < BB * NEXP) {
    float s = gate_b[tid & 7];
#pragma unroll
    for (int g = 0; g < 8; ++g) s += red[tid][g];
    sc[tid] = s;
  }
  __syncthreads();
  if (tid < BB) {
    int bb = tid;
    int i0 = 0; float v0 = sc[bb * 8 + 0];
    for (int ee = 1; ee < 8; ++ee) { float v = sc[bb * 8 + ee]; if (v > v0) { v0 = v; i0 = ee; } }
    int i1 = -1; float v1 = -1e30f;
    for (int ee = 0; ee < 8; ++ee) {
      if (ee == i0) continue;
      float v = sc[bb * 8 + ee];
      if (v > v1) { v1 = v; i1 = ee; }
    }
    float e1 = expf(v1 - v0);          // softmax with max-subtraction (v0 >= v1)
    float s = 1.f + e1;
    gs[bb * 2 + 0] = 1.f / s;  gidx[bb * 2 + 0] = i0;
    gs[bb * 2 + 1] = e1 / s;   gidx[bb * 2 + 1] = i1;
  }
  __syncthreads();
  if (tid < NEXP) {
    int ee = tid;
    float vals[32];
    bool used[32];
    for (int i = 0; i < 32; ++i) { vals[i] = (gidx[i] == ee) ? gs[i] : -1.0f; used[i] = false; }
    for (int s = 0; s < CAP; ++s) {   // top-CAP: value desc, index asc on ties
      int bi = -1; float bv = -1e30f;
      for (int i = 0; i < 32; ++i) {
        if (used[i]) continue;
        if (vals[i] > bv) { bv = vals[i]; bi = i; }
      }
      used[bi] = true;
      etok[ee * CAP + s] = bi >> 1;          // pos // TOPK
      ewt[ee * CAP + s] = bv > 0.f ? bv : 0.f;
    }
  }
}

// ---------------- MoE GEMM1: 64 blocks = 8 experts x 8 tiles of 64 HID cols ----
__global__ void __launch_bounds__(256) k_expert1(
    const float* __restrict__ rootA,
    const float* __restrict__ ew1, const float* __restrict__ eb1,
    const int* __restrict__ etok,
    float* __restrict__ hid_ws) {
  int bx = blockIdx.x;
  int e = bx >> 3, jt = bx & 7, j0 = jt * 64;
  int tid = threadIdx.x, w = tid >> 6, lane = tid & 63;
  __shared__ float xin[CAP][DIM];
  __shared__ float red[CAP][4][64];
  __shared__ int stok[CAP];
  if (tid < CAP) stok[tid] = etok[e * CAP + tid];
  __syncthreads();
  for (int idx = tid; idx < CAP * DIM; idx += 256) {
    int s = idx >> 8, k = idx & 255;
    xin[s][k] = rootA[stok[s] * DIM + k];
  }
  __syncthreads();
  float a0 = 0.f, a1 = 0.f, a2 = 0.f, a3 = 0.f, a4 = 0.f;
  const float* W = ew1 + (size_t)e * DIM * HID + j0 + lane;  // row k -> +k*HID
  int kbase = w * 64;
#pragma unroll
  for (int h = 0; h < 8; ++h) {
    float wv[8];
#pragma unroll
    for (int i = 0; i < 8; ++i) wv[i] = W[(size_t)(kbase + h * 8 + i) * HID];
#pragma unroll
    for (int i = 0; i < 8; ++i) {
      int k = kbase + h * 8 + i;
      a0 = fmaf(xin[0][k], wv[i], a0);
      a1 = fmaf(xin[1][k], wv[i], a1);
      a2 = fmaf(xin[2][k], wv[i], a2);
      a3 = fmaf(xin[3][k], wv[i], a3);
      a4 = fmaf(xin[4][k], wv[i], a4);
    }
  }
  red[0][w][lane] = a0; red[1][w][lane] = a1; red[2][w][lane] = a2;
  red[3][w][lane] = a3; red[4][w][lane] = a4;
  __syncthreads();
  for (int idx = tid; idx < CAP * 64; idx += 256) {
    int s = idx >> 6, j = idx & 63;
    float sum = red[s][0][j] + red[s][1][j] + red[s][2][j] + red[s][3][j]
              + eb1[e * HID + j0 + j];
    hid_ws[((size_t)(e * CAP + s)) * HID + j0 + j] = fmaxf(sum, 0.f);
  }
}

// ----- MoE GEMM2 + combine: 64 blocks; atomic add into root2[tok] -------------
__global__ void __launch_bounds__(256) k_expert2(
    const float* __restrict__ hid_ws,
    const float* __restrict__ ew2, const float* __restrict__ eb2,
    const float* __restrict__ ewt, const int* __restrict__ etok,
    float* __restrict__ root2) {
  int bx = blockIdx.x;
  int e = bx >> 3, dt = bx & 7, d0 = dt * 32;
  int tid = threadIdx.x, seg = tid >> 5, c = tid & 31;  // 8 segs x 64 k each
  __shared__ float hv[CAP][HID];
  __shared__ float red[CAP][8][32];
  for (int idx = tid; idx < CAP * HID; idx += 256) {
    int s = idx >> 9, k = idx & 511;
    hv[s][k] = hid_ws[((size_t)(e * CAP + s)) * HID + k];
  }
  __syncthreads();
  float a0 = 0.f, a1 = 0.f, a2 = 0.f, a3 = 0.f, a4 = 0.f;
  const float* W = ew2 + (size_t)e * HID * DIM + d0 + c;  // row k -> +k*DIM
  int kbase = seg * 64;
#pragma unroll
  for (int h = 0; h < 8; ++h) {
    float wv[8];
#pragma unroll
    for (int i = 0; i < 8; ++i) wv[i] = W[(size_t)(kbase + h * 8 + i) * DIM];
#pragma unroll
    for (int i = 0; i < 8; ++i) {
      int k = kbase + h * 8 + i;
      a0 = fmaf(hv[0][k], wv[i], a0);
      a1 = fmaf(hv[1][k], wv[i], a1);
      a2 = fmaf(hv[2][k], wv[i], a2);
      a3 = fmaf(hv[3][k], wv[i], a3);
      a4 = fmaf(hv[4][k], wv[i], a4);
    }
  }
  red[0][seg][c] = a0; red[1][seg][c] = a1; red[2][seg][c] = a2;
  red[3][seg][c] = a3; red[4][seg][c] = a4;
  __syncthreads();
  if (tid < CAP * 32) {
    int s = tid >> 5, cc = tid & 31;
    float sum = 0.f;
#pragma unroll
    for (int g = 0; g < 8; ++g) sum += red[s][g][cc];
    sum += eb2[e * DIM + d0 + cc];
    float w = ewt[e * CAP + s];
    if (w > 0.f)
      atomicAdd(&root2[etok[e * CAP + s] * DIM + d0 + cc], sum * w);
  }
}

// ---- logits table: grid (257 tokens x 4 rowgroups) x 256 threads ------------
__global__ void __launch_bounds__(256) k_table(
    const float* __restrict__ embed, const float* __restrict__ root2,
    const float* __restrict__ hw1, const float* __restrict__ hb1,
    const float* __restrict__ hw2, const float* __restrict__ hb2,
    float* __restrict__ table) {
  int tok = blockIdx.x, r0 = blockIdx.y * 4;
  int c = threadIdx.x;
  __shared__ float hrow[4][DIM];
  __shared__ float hid[4][DIM];
  __shared__ float tailred[4][17];
  {
    float ev = embed[(size_t)tok * DIM + c];
#pragma unroll
    for (int j = 0; j < 4; ++j) hrow[j][c] = ev + root2[(size_t)(r0 + j) * DIM + c];
  }
  __syncthreads();
  // GEMM1: col c over K=256, 4 rows
  {
    float a0 = hb1[c], a1 = a0, a2 = a0, a3 = a0;
    for (int kb = 0; kb < DIM; kb += 8) {
      float wv[8];
#pragma unroll
      for (int i = 0; i < 8; ++i) wv[i] = hw1[(size_t)(kb + i) * DIM + c];
#pragma unroll
      for (int i = 0; i < 8; ++i) {
        int k = kb + i;
        a0 = fmaf(hrow[0][k], wv[i], a0);
        a1 = fmaf(hrow[1][k], wv[i], a1);
        a2 = fmaf(hrow[2][k], wv[i], a2);
        a3 = fmaf(hrow[3][k], wv[i], a3);
      }
    }
    hid[0][c] = fmaxf(a0, 0.f); hid[1][c] = fmaxf(a1, 0.f);
    hid[2][c] = fmaxf(a2, 0.f); hid[3][c] = fmaxf(a3, 0.f);
  }
  __syncthreads();
  // GEMM2: cols 0..255
  {
    float a0 = hb2[c], a1 = a0, a2 = a0, a3 = a0;
    for (int kb = 0; kb < DIM; kb += 8) {
      float wv[8];
#pragma unroll
      for (int i = 0; i < 8; ++i) wv[i] = hw2[(size_t)(kb + i) * VOCAB + c];
#pragma unroll
      for (int i = 0; i < 8; ++i) {
        int k = kb + i;
        a0 = fmaf(hid[0][k], wv[i], a0);
        a1 = fmaf(hid[1][k], wv[i], a1);
        a2 = fmaf(hid[2][k], wv[i], a2);
        a3 = fmaf(hid[3][k], wv[i], a3);
      }
    }
    table[((size_t)((r0 + 0) * VOCAB + tok)) * TSTR + c] = a0;
    table[((size_t)((r0 + 1) * VOCAB + tok)) * TSTR + c] = a1;
    table[((size_t)((r0 + 2) * VOCAB + tok)) * TSTR + c] = a2;
    table[((size_t)((r0 + 3) * VOCAB + tok)) * TSTR + c] = a3;
  }
  // tail column 256: 16-way K-split across first 64 threads
  if (c < 64) {
    int r = c >> 4, seg = c & 15;
    float sum = 0.f;
#pragma unroll 4
    for (int i = 0; i < 16; ++i) {
      int k = seg * 16 + i;
      sum = fmaf(hid[r][k], hw2[(size_t)k * VOCAB + 256], sum);
    }
    tailred[r][seg] = sum;
  }
  __syncthreads();
  if (c < 4) {
    float a = hb2[256];
#pragma unroll
    for (int s = 0; s < 16; ++s) a += tailred[c][s];
    table[((size_t)((r0 + c) * VOCAB + tok)) * TSTR + 256] = a;
  }
}

// ---------------- scatter: out flat, 1 element/thread, coalesced -------------
// out[b,t,c] = table[(b*257 + tokens[b*T+t])*260 + c]
__global__ void __launch_bounds__(1024) k_scatter(const int* __restrict__ tokens,
                                                  const float* __restrict__ table,
                                                  float* __restrict__ out) {
  int f = blockIdx.x * 1024 + threadIdx.x;   // < 16*2048*257 = 8,421,376
  int row = (int)((unsigned)f / 257u);       // b*T + t  (compiler magic-mul)
  int c = f - row * 257;
  int b = row >> 11;                         // T = 2048
  int tok = tokens[row];
  out[f] = table[((size_t)(b * VOCAB + tok)) * TSTR + c];
}

extern "C" void kernel_launch(void* const* d_in, const int* in_sizes, int n_in,
                              void* d_out, int out_size, void* d_ws, size_t ws_size,
                              hipStream_t stream) {
  (void)in_sizes; (void)n_in; (void)out_size; (void)ws_size;
  const int*   tokens     = (const int*)d_in[0];
  const float* embed      = (const float*)d_in[1];
  const float* pin_w      = (const float*)d_in[2];
  const float* pin_b      = (const float*)d_in[3];
  const float* pch_w      = (const float*)d_in[4];
  const float* pch_b      = (const float*)d_in[5];
  const float* depth_bias = (const float*)d_in[6];
  // d_in[7..10] = q_w,q_b,k_w,k_b: provably unused (uniform softmax)
  const float* v_w        = (const float*)d_in[11];
  const float* v_b        = (const float*)d_in[12];
  const float* o_w        = (const float*)d_in[13];
  const float* o_b        = (const float*)d_in[14];
  const float* level_gate = (const float*)d_in[15];
  const float* depth_gate = (const float*)d_in[16];
  const float* in_proj_w  = (const float*)d_in[17];
  const float* in_proj_b  = (const float*)d_in[18];
  const float* out_proj_w = (const float*)d_in[19];
  const float* out_proj_b = (const float*)d_in[20];
  const float* ln_g       = (const float*)d_in[21];
  const float* ln_b       = (const float*)d_in[22];
  const float* ic_gate    = (const float*)d_in[23];
  const float* gate_w     = (const float*)d_in[24];
  const float* gate_b     = (const float*)d_in[25];
  const float* ew1        = (const float*)d_in[26];
  const float* eb1        = (const float*)d_in[27];
  const float* ew2        = (const float*)d_in[28];
  const float* eb2        = (const float*)d_in[29];
  const float* hw1        = (const float*)d_in[30];
  const float* hb1        = (const float*)d_in[31];
  const float* hw2        = (const float*)d_in[32];
  const float* hb2        = (const float*)d_in[33];
  float* out = (float*)d_out;

  float* ws      = (float*)d_ws;
  float* rootA   = ws + 4096;          // 4096
  float* root2   = ws + 8192;          // 4096
  int*   etok    = (int*)(ws + 22528); // 40
  float* ewt     = ws + 22576;         // 40
  float* table   = ws + 22656;         // 16*257*260 = 1,069,120 floats (~4.4 MB)
  // hid_ws aliases table region (dead before k_table writes it; in-order stream)
  float* hid_ws  = table;

  k_fractal<<<BB, 1024, 0, stream>>>(tokens, embed, pin_w, pin_b, pch_w, pch_b,
                                     depth_bias, v_w, v_b, o_w, o_b, level_gate,
                                     depth_gate, in_proj_w, in_proj_b, out_proj_w,
                                     out_proj_b, ln_g, ln_b, ic_gate, rootA);
  k_gate<<<1, 1024, 0, stream>>>(rootA, gate_w, gate_b, etok, ewt, root2);
  k_expert1<<<NEXP * 8, 256, 0, stream>>>(rootA, ew1, eb1, etok, hid_ws);
  k_expert2<<<NEXP * 8, 256, 0, stream>>>(hid_ws, ew2, eb2, ewt, etok, root2);
  k_table<<<dim3(VOCAB, 4), 256, 0, stream>>>(embed, root2, hw1, hb1, hw2, hb2, table);
  k_scatter<<<(BB * TT * VOCAB) / 1024, 1024, 0, stream>>>(tokens, table, out);
}

// Round 11
// 268.922 us; speedup vs baseline: 1.4716x; 1.4716x over previous
//
#include <hip/hip_runtime.h>
#include <hip/hip_bf16.h>
#include <math.h>

#define DIM    256
#define DEPTH  5
#define FANOUT 10
#define VOCAB  257
#define BB     16
#define TT     2048
#define NEXP   8
#define HID    512
#define TOPK   2
#define CAP    5   // ceil(16*2/8*1.1)
#define TSTR   260 // padded table row stride (16B-aligned, float4-clean)

__device__ __forceinline__ float sigm(float x) { return 1.f / (1.f + expf(-x)); }

// partial dot over k in [k0,k0+64): R4/R6-proven form (VGPR-light, no spill)
__device__ __forceinline__ float dotcol64(const float* sv, const float* __restrict__ W,
                                          int col, int k0, int stride) {
  float acc = 0.f;
#pragma unroll 8
  for (int i = 0; i < 64; ++i) {
    int k = k0 + i;
    acc = fmaf(sv[k], W[(size_t)k * stride + col], acc);
  }
  return acc;
}

// ------ collapsed fractal (context fused in): 16 blocks x 1024 threads -------
// VERBATIM R6 kernel: benched 76.9 us, VGPR 44, WRITE_SIZE 16 KB (no spill).
__global__ void __launch_bounds__(1024) k_fractal(
    const int* __restrict__ tokens, const float* __restrict__ embed,
    const float* __restrict__ pin_w, const float* __restrict__ pin_b,
    const float* __restrict__ pch_w, const float* __restrict__ pch_b,
    const float* __restrict__ depth_bias,
    const float* __restrict__ v_w, const float* __restrict__ v_b,
    const float* __restrict__ o_w, const float* __restrict__ o_b,
    const float* __restrict__ level_gate, const float* __restrict__ depth_gate,
    const float* __restrict__ in_proj_w, const float* __restrict__ in_proj_b,
    const float* __restrict__ out_proj_w, const float* __restrict__ out_proj_b,
    const float* __restrict__ ln_g, const float* __restrict__ ln_b,
    const float* __restrict__ ic_gate,
    float* __restrict__ rootA) {
  int b = blockIdx.x;
  int tid = threadIdx.x;
  int d = tid & 255;
  int ks = tid >> 8;       // 0..3
  int k0 = ks * 64;
  __shared__ int cnt[VOCAB];
  __shared__ float sv[DIM];
  __shared__ float basev[DIM];
  __shared__ float ym[DEPTH][DIM];
  __shared__ float q0v[DIM], kh[DEPTH][DIM], vh[DEPTH][DIM];
  __shared__ float red4[4][DIM];
  __shared__ float red11[4][11][DIM];   // fused in_proj reduction
  __shared__ float zsv[DIM];
  __shared__ float aw[16];
  __shared__ float redl[8];

  // ---- context = (histogram @ embed) / T, branch-free, K-split over vocab ----
  for (int i = tid; i < VOCAB; i += 1024) cnt[i] = 0;
  __syncthreads();
  for (int t = tid; t < TT; t += 1024) atomicAdd(&cnt[tokens[b * TT + t]], 1);
  __syncthreads();
  {
    float acc = 0.f;
#pragma unroll
    for (int h = 0; h < 2; ++h) {
      int vb = ks * 64 + h * 32;
      float ev[32], cv[32];
#pragma unroll
      for (int i = 0; i < 32; ++i) ev[i] = embed[(size_t)(vb + i) * DIM + d];
#pragma unroll
      for (int i = 0; i < 32; ++i) cv[i] = (float)cnt[vb + i];
#pragma unroll
      for (int i = 0; i < 32; ++i) acc = fmaf(cv[i], ev[i], acc);
    }
    if (ks == 0) acc = fmaf((float)cnt[256], embed[(size_t)256 * DIM + d], acc);
    red4[ks][d] = acc;
  }
  __syncthreads();
  if (ks == 0)
    sv[d] = (red4[0][d] + red4[1][d] + red4[2][d] + red4[3][d]) * (1.0f / (float)TT);
  __syncthreads();

  // base = context @ pin_w + pin_b ; level-4 elementwise (child_agg == 0)
  red4[ks][d] = dotcol64(sv, pin_w, d, k0, DIM);
  __syncthreads();
  if (ks == 0) {
    float base = red4[0][d] + red4[1][d] + red4[2][d] + red4[3][d] + pin_b[d];
    basev[d] = base;
    float u = (base + depth_bias[4 * DIM + d] + pch_b[d]) * sigm(level_gate[4]);
    sv[d] = fmaxf(u, 0.f);
  }
  __syncthreads();
  red4[ks][d] = dotcol64(sv, o_w, d, k0, DIM);
  __syncthreads();
  if (ks == 0) {
    float y = red4[0][d] + red4[1][d] + red4[2][d] + red4[3][d] + o_b[d];
    ym[4][d] = y;
    sv[d] = y;
  }
  __syncthreads();
  for (int l = 3; l >= 0; --l) {
    red4[ks][d] = dotcol64(sv, v_w, d, k0, DIM);
    __syncthreads();
    if (ks == 0) {
      float vv = red4[0][d] + red4[1][d] + red4[2][d] + red4[3][d] + v_b[d];
      sv[d] = sigm(depth_gate[l * DIM + d]) * vv;   // uniform softmax -> child = v
    }
    __syncthreads();
    red4[ks][d] = dotcol64(sv, pch_w, d, k0, DIM);
    __syncthreads();
    if (ks == 0) {
      float t = red4[0][d] + red4[1][d] + red4[2][d] + red4[3][d] + pch_b[d];
      float u = (basev[d] + depth_bias[l * DIM + d] + t) * sigm(level_gate[l]);
      sv[d] = fmaxf(u, 0.f);
    }
    __syncthreads();
    red4[ks][d] = dotcol64(sv, o_w, d, k0, DIM);
    __syncthreads();
    if (ks == 0) {
      float y = red4[0][d] + red4[1][d] + red4[2][d] + red4[3][d] + o_b[d];
      ym[l][d] = y;
      sv[d] = y;
    }
    __syncthreads();
  }
  // ---- in_proj, ALL levels in ONE pass over the weights ----
  {
    float aq = 0.f;
    float ak0 = 0.f, ak1 = 0.f, ak2 = 0.f, ak3 = 0.f, ak4 = 0.f;
    float av0 = 0.f, av1 = 0.f, av2 = 0.f, av3 = 0.f, av4 = 0.f;
#pragma unroll
    for (int h = 0; h < 8; ++h) {
      int kb = k0 + h * 8;
      float wq[8], wk[8], wv8[8];
#pragma unroll
      for (int i = 0; i < 8; ++i) {
        const float* wrow = in_proj_w + (size_t)(kb + i) * 768;
        wq[i] = wrow[d]; wk[i] = wrow[256 + d]; wv8[i] = wrow[512 + d];
      }
#pragma unroll
      for (int i = 0; i < 8; ++i) {
        float z0 = ym[0][kb + i];
        aq  = fmaf(z0, wq[i], aq);
        ak0 = fmaf(z0, wk[i], ak0);
        av0 = fmaf(z0, wv8[i], av0);
        float z1 = ym[1][kb + i];
        ak1 = fmaf(z1, wk[i], ak1);
        av1 = fmaf(z1, wv8[i], av1);
        float z2 = ym[2][kb + i];
        ak2 = fmaf(z2, wk[i], ak2);
        av2 = fmaf(z2, wv8[i], av2);
        float z3 = ym[3][kb + i];
        ak3 = fmaf(z3, wk[i], ak3);
        av3 = fmaf(z3, wv8[i], av3);
        float z4 = ym[4][kb + i];
        ak4 = fmaf(z4, wk[i], ak4);
        av4 = fmaf(z4, wv8[i], av4);
      }
    }
    red11[ks][0][d] = ak0; red11[ks][1][d] = ak1; red11[ks][2][d] = ak2;
    red11[ks][3][d] = ak3; red11[ks][4][d] = ak4;
    red11[ks][5][d] = av0; red11[ks][6][d] = av1; red11[ks][7][d] = av2;
    red11[ks][8][d] = av3; red11[ks][9][d] = av4;
    red11[ks][10][d] = aq;
  }
  __syncthreads();
  for (int idx = tid; idx < 11 * DIM; idx += 1024) {
    int c = idx >> 8, dd = idx & 255;
    float sum = red11[0][c][dd] + red11[1][c][dd] + red11[2][c][dd] + red11[3][c][dd];
    if (c < 5)       kh[c][dd]     = sum + in_proj_b[256 + dd];
    else if (c < 10) vh[c - 5][dd] = sum + in_proj_b[512 + dd];
    else             q0v[dd]       = sum + in_proj_b[dd];
  }
  __syncthreads();
  if (tid < 10) {  // scores for (head, level)
    int h = tid / 5, l = tid - h * 5;
    float s = 0.f;
    for (int j = 0; j < 128; ++j) s = fmaf(q0v[h * 128 + j], kh[l][h * 128 + j], s);
    aw[tid] = s * 0.08838834764831845f;  // 1/sqrt(128)
  }
  __syncthreads();
  if (tid < 2) {  // softmax per head
    float m = aw[tid * 5];
    for (int l = 1; l < 5; ++l) m = fmaxf(m, aw[tid * 5 + l]);
    float e[5], ssum = 0.f;
    for (int l = 0; l < 5; ++l) { e[l] = expf(aw[tid * 5 + l] - m); ssum += e[l]; }
    for (int l = 0; l < 5; ++l) aw[tid * 5 + l] = e[l] / ssum;
  }
  __syncthreads();
  if (ks == 0) {
    int h = d >> 7;
    float z2 = 0.f;
    for (int l = 0; l < 5; ++l) z2 = fmaf(aw[h * 5 + l], vh[l][d], z2);
    sv[d] = z2;
  }
  __syncthreads();
  red4[ks][d] = dotcol64(sv, out_proj_w, d, k0, DIM);
  __syncthreads();
  if (ks == 0) {
    float z2p = red4[0][d] + red4[1][d] + red4[2][d] + red4[3][d] + out_proj_b[d];
    zsv[d] = ym[0][d] + z2p;
  }
  __syncthreads();
  // layernorm over 256 (waves 0..3 only)
  float zs = 0.f, df = 0.f, mu = 0.f;
  if (tid < 256) {
    zs = zsv[tid];
    float v = zs;
    for (int o = 32; o > 0; o >>= 1) v += __shfl_down(v, o, 64);
    if ((tid & 63) == 0) redl[tid >> 6] = v;
  }
  __syncthreads();
  if (tid < 256) {
    mu = (redl[0] + redl[1] + redl[2] + redl[3]) * (1.f / 256.f);
    df = zs - mu;
  }
  __syncthreads();
  if (tid < 256) {
    float v = df * df;
    for (int o = 32; o > 0; o >>= 1) v += __shfl_down(v, o, 64);
    if ((tid & 63) == 0) redl[tid >> 6] = v;
  }
  __syncthreads();
  if (tid < 256) {
    float var = (redl[0] + redl[1] + redl[2] + redl[3]) * (1.f / 256.f);
    float zn = df / sqrtf(var + 1e-5f) * ln_g[tid] + ln_b[tid];
    rootA[b * DIM + tid] = ym[0][tid] + sigm(ic_gate[0]) * zn;
  }
}

// ------- MoE gating + root2 init: exact lax.top_k semantics -------------------
__global__ void __launch_bounds__(1024) k_gate(const float* __restrict__ rootA,
                                               const float* __restrict__ gate_w,
                                               const float* __restrict__ gate_b,
                                               int* __restrict__ etok,
                                               float* __restrict__ ewt,
                                               float* __restrict__ root2) {
  __shared__ float red[BB * NEXP][9];   // pad to 9 -> conflict-light
  __shared__ float sc[BB * NEXP];
  __shared__ float gs[BB * TOPK];
  __shared__ int gidx[BB * TOPK];
  int tid = threadIdx.x;
  int be = tid >> 3, ks = tid & 7;      // be = b*8+e, 8-way K-split
  int b = be >> 3, e = be & 7;
  {
    float acc = 0.f;
#pragma unroll 8
    for (int i = 0; i < 32; ++i) {
      int k = ks * 32 + i;
      acc = fmaf(rootA[b * DIM + k], gate_w[k * NEXP + e], acc);
    }
    red[be][ks] = acc;
  }
  // root2 = rootA (experts atomically add on top)
  for (int i = tid; i < BB * DIM; i += 1024) root2[i] = rootA[i];
  __syncthreads();
  if (tid < BB * NEXP) {
    float s = gate_b[tid & 7];
#pragma unroll
    for (int g = 0; g < 8; ++g) s += red[tid][g];
    sc[tid] = s;
  }
  __syncthreads();
  if (tid < BB) {
    int bb = tid;
    int i0 = 0; float v0 = sc[bb * 8 + 0];
    for (int ee = 1; ee < 8; ++ee) { float v = sc[bb * 8 + ee]; if (v > v0) { v0 = v; i0 = ee; } }
    int i1 = -1; float v1 = -1e30f;
    for (int ee = 0; ee < 8; ++ee) {
      if (ee == i0) continue;
      float v = sc[bb * 8 + ee];
      if (v > v1) { v1 = v; i1 = ee; }
    }
    float e1 = expf(v1 - v0);          // softmax with max-subtraction (v0 >= v1)
    float s = 1.f + e1;
    gs[bb * 2 + 0] = 1.f / s;  gidx[bb * 2 + 0] = i0;
    gs[bb * 2 + 1] = e1 / s;   gidx[bb * 2 + 1] = i1;
  }
  __syncthreads();
  if (tid < NEXP) {
    int ee = tid;
    float vals[32];
    bool used[32];
    for (int i = 0; i < 32; ++i) { vals[i] = (gidx[i] == ee) ? gs[i] : -1.0f; used[i] = false; }
    for (int s = 0; s < CAP; ++s) {   // top-CAP: value desc, index asc on ties
      int bi = -1; float bv = -1e30f;
      for (int i = 0; i < 32; ++i) {
        if (used[i]) continue;
        if (vals[i] > bv) { bv = vals[i]; bi = i; }
      }
      used[bi] = true;
      etok[ee * CAP + s] = bi >> 1;          // pos // TOPK
      ewt[ee * CAP + s] = bv > 0.f ? bv : 0.f;
    }
  }
}

// ---------------- MoE GEMM1: 64 blocks = 8 experts x 8 tiles of 64 HID cols ----
__global__ void __launch_bounds__(256) k_expert1(
    const float* __restrict__ rootA,
    const float* __restrict__ ew1, const float* __restrict__ eb1,
    const int* __restrict__ etok,
    float* __restrict__ hid_ws) {
  int bx = blockIdx.x;
  int e = bx >> 3, jt = bx & 7, j0 = jt * 64;
  int tid = threadIdx.x, w = tid >> 6, lane = tid & 63;
  __shared__ float xin[CAP][DIM];
  __shared__ float red[CAP][4][64];
  __shared__ int stok[CAP];
  if (tid < CAP) stok[tid] = etok[e * CAP + tid];
  __syncthreads();
  for (int idx = tid; idx < CAP * DIM; idx += 256) {
    int s = idx >> 8, k = idx & 255;
    xin[s][k] = rootA[stok[s] * DIM + k];
  }
  __syncthreads();
  float a0 = 0.f, a1 = 0.f, a2 = 0.f, a3 = 0.f, a4 = 0.f;
  const float* W = ew1 + (size_t)e * DIM * HID + j0 + lane;  // row k -> +k*HID
  int kbase = w * 64;
#pragma unroll
  for (int h = 0; h < 8; ++h) {
    float wv[8];
#pragma unroll
    for (int i = 0; i < 8; ++i) wv[i] = W[(size_t)(kbase + h * 8 + i) * HID];
#pragma unroll
    for (int i = 0; i < 8; ++i) {
      int k = kbase + h * 8 + i;
      a0 = fmaf(xin[0][k], wv[i], a0);
      a1 = fmaf(xin[1][k], wv[i], a1);
      a2 = fmaf(xin[2][k], wv[i], a2);
      a3 = fmaf(xin[3][k], wv[i], a3);
      a4 = fmaf(xin[4][k], wv[i], a4);
    }
  }
  red[0][w][lane] = a0; red[1][w][lane] = a1; red[2][w][lane] = a2;
  red[3][w][lane] = a3; red[4][w][lane] = a4;
  __syncthreads();
  for (int idx = tid; idx < CAP * 64; idx += 256) {
    int s = idx >> 6, j = idx & 63;
    float sum = red[s][0][j] + red[s][1][j] + red[s][2][j] + red[s][3][j]
              + eb1[e * HID + j0 + j];
    hid_ws[((size_t)(e * CAP + s)) * HID + j0 + j] = fmaxf(sum, 0.f);
  }
}

// ----- MoE GEMM2 + combine: 64 blocks; atomic add into root2[tok] -------------
__global__ void __launch_bounds__(256) k_expert2(
    const float* __restrict__ hid_ws,
    const float* __restrict__ ew2, const float* __restrict__ eb2,
    const float* __restrict__ ewt, const int* __restrict__ etok,
    float* __restrict__ root2) {
  int bx = blockIdx.x;
  int e = bx >> 3, dt = bx & 7, d0 = dt * 32;
  int tid = threadIdx.x, seg = tid >> 5, c = tid & 31;  // 8 segs x 64 k each
  __shared__ float hv[CAP][HID];
  __shared__ float red[CAP][8][32];
  for (int idx = tid; idx < CAP * HID; idx += 256) {
    int s = idx >> 9, k = idx & 511;
    hv[s][k] = hid_ws[((size_t)(e * CAP + s)) * HID + k];
  }
  __syncthreads();
  float a0 = 0.f, a1 = 0.f, a2 = 0.f, a3 = 0.f, a4 = 0.f;
  const float* W = ew2 + (size_t)e * HID * DIM + d0 + c;  // row k -> +k*DIM
  int kbase = seg * 64;
#pragma unroll
  for (int h = 0; h < 8; ++h) {
    float wv[8];
#pragma unroll
    for (int i = 0; i < 8; ++i) wv[i] = W[(size_t)(kbase + h * 8 + i) * DIM];
#pragma unroll
    for (int i = 0; i < 8; ++i) {
      int k = kbase + h * 8 + i;
      a0 = fmaf(hv[0][k], wv[i], a0);
      a1 = fmaf(hv[1][k], wv[i], a1);
      a2 = fmaf(hv[2][k], wv[i], a2);
      a3 = fmaf(hv[3][k], wv[i], a3);
      a4 = fmaf(hv[4][k], wv[i], a4);
    }
  }
  red[0][seg][c] = a0; red[1][seg][c] = a1; red[2][seg][c] = a2;
  red[3][seg][c] = a3; red[4][seg][c] = a4;
  __syncthreads();
  if (tid < CAP * 32) {
    int s = tid >> 5, cc = tid & 31;
    float sum = 0.f;
#pragma unroll
    for (int g = 0; g < 8; ++g) sum += red[s][g][cc];
    sum += eb2[e * DIM + d0 + cc];
    float w = ewt[e * CAP + s];
    if (w > 0.f)
      atomicAdd(&root2[etok[e * CAP + s] * DIM + d0 + cc], sum * w);
  }
}

// ---- logits table: grid (257 tokens x 4 rowgroups) x 256 threads ------------
__global__ void __launch_bounds__(256) k_table(
    const float* __restrict__ embed, const float* __restrict__ root2,
    const float* __restrict__ hw1, const float* __restrict__ hb1,
    const float* __restrict__ hw2, const float* __restrict__ hb2,
    float* __restrict__ table) {
  int tok = blockIdx.x, r0 = blockIdx.y * 4;
  int c = threadIdx.x;
  __shared__ float hrow[4][DIM];
  __shared__ float hid[4][DIM];
  __shared__ float tailred[4][17];
  {
    float ev = embed[(size_t)tok * DIM + c];
#pragma unroll
    for (int j = 0; j < 4; ++j) hrow[j][c] = ev + root2[(size_t)(r0 + j) * DIM + c];
  }
  __syncthreads();
  // GEMM1: col c over K=256, 4 rows
  {
    float a0 = hb1[c], a1 = a0, a2 = a0, a3 = a0;
    for (int kb = 0; kb < DIM; kb += 8) {
      float wv[8];
#pragma unroll
      for (int i = 0; i < 8; ++i) wv[i] = hw1[(size_t)(kb + i) * DIM + c];
#pragma unroll
      for (int i = 0; i < 8; ++i) {
        int k = kb + i;
        a0 = fmaf(hrow[0][k], wv[i], a0);
        a1 = fmaf(hrow[1][k], wv[i], a1);
        a2 = fmaf(hrow[2][k], wv[i], a2);
        a3 = fmaf(hrow[3][k], wv[i], a3);
      }
    }
    hid[0][c] = fmaxf(a0, 0.f); hid[1][c] = fmaxf(a1, 0.f);
    hid[2][c] = fmaxf(a2, 0.f); hid[3][c] = fmaxf(a3, 0.f);
  }
  __syncthreads();
  // GEMM2: cols 0..255
  {
    float a0 = hb2[c], a1 = a0, a2 = a0, a3 = a0;
    for (int kb = 0; kb < DIM; kb += 8) {
      float wv[8];
#pragma unroll
      for (int i = 0; i < 8; ++i) wv[i] = hw2[(size_t)(kb + i) * VOCAB + c];
#pragma unroll
      for (int i = 0; i < 8; ++i) {
        int k = kb + i;
        a0 = fmaf(hid[0][k], wv[i], a0);
        a1 = fmaf(hid[1][k], wv[i], a1);
        a2 = fmaf(hid[2][k], wv[i], a2);
        a3 = fmaf(hid[3][k], wv[i], a3);
      }
    }
    table[((size_t)((r0 + 0) * VOCAB + tok)) * TSTR + c] = a0;
    table[((size_t)((r0 + 1) * VOCAB + tok)) * TSTR + c] = a1;
    table[((size_t)((r0 + 2) * VOCAB + tok)) * TSTR + c] = a2;
    table[((size_t)((r0 + 3) * VOCAB + tok)) * TSTR + c] = a3;
  }
  // tail column 256: 16-way K-split across first 64 threads
  if (c < 64) {
    int r = c >> 4, seg = c & 15;
    float sum = 0.f;
#pragma unroll 4
    for (int i = 0; i < 16; ++i) {
      int k = seg * 16 + i;
      sum = fmaf(hid[r][k], hw2[(size_t)k * VOCAB + 256], sum);
    }
    tailred[r][seg] = sum;
  }
  __syncthreads();
  if (c < 4) {
    float a = hb2[256];
#pragma unroll
    for (int s = 0; s < 16; ++s) a += tailred[c][s];
    table[((size_t)((r0 + c) * VOCAB + tok)) * TSTR + 256] = a;
  }
}

// ---------------- scatter: out flat, 1 element/thread, coalesced -------------
// out[b,t,c] = table[(b*257 + tokens[b*T+t])*260 + c]
__global__ void __launch_bounds__(1024) k_scatter(const int* __restrict__ tokens,
                                                  const float* __restrict__ table,
                                                  float* __restrict__ out) {
  int f = blockIdx.x * 1024 + threadIdx.x;   // < 16*2048*257 = 8,421,376
  int row = (int)((unsigned)f / 257u);       // b*T + t  (compiler magic-mul)
  int c = f - row * 257;
  int b = row >> 11;                         // T = 2048
  int tok = tokens[row];
  out[f] = table[((size_t)(b * VOCAB + tok)) * TSTR + c];
}

extern "C" void kernel_launch(void* const* d_in, const int* in_sizes, int n_in,
                              void* d_out, int out_size, void* d_ws, size_t ws_size,
                              hipStream_t stream) {
  (void)in_sizes; (void)n_in; (void)out_size; (void)ws_size;
  const int*   tokens     = (const int*)d_in[0];
  const float* embed      = (const float*)d_in[1];
  const float* pin_w      = (const float*)d_in[2];
  const float* pin_b      = (const float*)d_in[3];
  const float* pch_w      = (const float*)d_in[4];
  const float* pch_b      = (const float*)d_in[5];
  const float* depth_bias = (const float*)d_in[6];
  // d_in[7..10] = q_w,q_b,k_w,k_b: provably unused (uniform softmax)
  const float* v_w        = (const float*)d_in[11];
  const float* v_b        = (const float*)d_in[12];
  const float* o_w        = (const float*)d_in[13];
  const float* o_b        = (const float*)d_in[14];
  const float* level_gate = (const float*)d_in[15];
  const float* depth_gate = (const float*)d_in[16];
  const float* in_proj_w  = (const float*)d_in[17];
  const float* in_proj_b  = (const float*)d_in[18];
  const float* out_proj_w = (const float*)d_in[19];
  const float* out_proj_b = (const float*)d_in[20];
  const float* ln_g       = (const float*)d_in[21];
  const float* ln_b       = (const float*)d_in[22];
  const float* ic_gate    = (const float*)d_in[23];
  const float* gate_w     = (const float*)d_in[24];
  const float* gate_b     = (const float*)d_in[25];
  const float* ew1        = (const float*)d_in[26];
  const float* eb1        = (const float*)d_in[27];
  const float* ew2        = (const float*)d_in[28];
  const float* eb2        = (const float*)d_in[29];
  const float* hw1        = (const float*)d_in[30];
  const float* hb1        = (const float*)d_in[31];
  const float* hw2        = (const float*)d_in[32];
  const float* hb2        = (const float*)d_in[33];
  float* out = (float*)d_out;

  float* ws      = (float*)d_ws;
  float* rootA   = ws + 4096;          // 4096
  float* root2   = ws + 8192;          // 4096
  int*   etok    = (int*)(ws + 22528); // 40
  float* ewt     = ws + 22576;         // 40
  float* table   = ws + 22656;         // 16*257*260 = 1,069,120 floats (~4.4 MB)
  // hid_ws aliases table region (dead before k_table writes it; in-order stream)
  float* hid_ws  = table;

  k_fractal<<<BB, 1024, 0, stream>>>(tokens, embed, pin_w, pin_b, pch_w, pch_b,
                                     depth_bias, v_w, v_b, o_w, o_b, level_gate,
                                     depth_gate, in_proj_w, in_proj_b, out_proj_w,
                                     out_proj_b, ln_g, ln_b, ic_gate, rootA);
  k_gate<<<1, 1024, 0, stream>>>(rootA, gate_w, gate_b, etok, ewt, root2);
  k_expert1<<<NEXP * 8, 256, 0, stream>>>(rootA, ew1, eb1, etok, hid_ws);
  k_expert2<<<NEXP * 8, 256, 0, stream>>>(hid_ws, ew2, eb2, ewt, etok, root2);
  k_table<<<dim3(VOCAB, 4), 256, 0, stream>>>(embed, root2, hw1, hb1, hw2, hb2, table);
  k_scatter<<<(BB * TT * VOCAB) / 1024, 1024, 0, stream>>>(tokens, table, out);
}